// Round 5
// baseline (4571.631 us; speedup 1.0000x reference)
//
#include <hip/hip_runtime.h>

// TransportKernel: loss = ||k_ZZ||_F^2 - 2||k_ZY||_F^2 + 0.01 * tr(Z^T (K_XX+1e-3 I)^{-1} Z)
// Cholesky A=LL^T; tr = ||L^{-1}Z||_F^2. One fused kernel per 64-col step:
//   group T: substitution-TRSM col g (writes Lpanel, NOT A -> no WAR race) + W updates
//   group P: within-panel rank-64 updates (redundant self-TRSM of needed tiles)
//   group D: next diag block: self-TRSM + SYRK + wave-chol + W absorb/solve
// Every 4 steps: k_upd256p rank-256 trailing SYRK (reads Lpanel) + fused next-head chol.

#define NN 4096
#define LDA 4100
#define OFF_W   ((size_t)NN*LDA)
#define OFF_LP  (OFF_W + (size_t)NN*4)
#define OFF_ACC (OFF_LP + (size_t)4096*256)

__device__ __forceinline__ float rdlane(float v, int l){
    return __int_as_float(__builtin_amdgcn_readlane(__float_as_int(v), l));
}

// ------------------------------------------------------------------
// chol64 of Dm (stride 68), write L to A(h,h), then solve L y = w, write W block.
// Called by lanes 0..63 of wave 0 only.
__device__ void wave_chol_solve(const float* Dm, float* __restrict__ A, int h,
                                float4 w, float* __restrict__ W){
    const int lane = threadIdx.x & 63;
    float row[64];
#pragma unroll
    for (int q=0;q<16;q++){
        float4 v = *(const float4*)(Dm + lane*68 + q*4);
        row[q*4]=v.x; row[q*4+1]=v.y; row[q*4+2]=v.z; row[q*4+3]=v.w;
    }
#pragma unroll
    for (int j=0;j<64;j++){
        float d  = rdlane(row[j], j);
        float sd = sqrtf(d);
        float inv= 1.0f/sd;
        float v  = (lane==j)? sd : row[j]*inv;
        row[j] = v;
#pragma unroll
        for (int c=j+1;c<64;c++){
            float lc = rdlane(v, c);
            row[c] -= v*lc;
        }
    }
#pragma unroll
    for (int q=0;q<16;q++)
        *(float4*)(A + (size_t)(h+lane)*LDA + h + q*4) =
            make_float4(row[q*4],row[q*4+1],row[q*4+2],row[q*4+3]);
    float w0=w.x,w1=w.y,w2=w.z,w3=w.w;
#pragma unroll
    for (int j=0;j<64;j++){
        if (lane==j){ float dj=1.0f/row[j]; w0*=dj; w1*=dj; w2*=dj; w3*=dj; }
        float b0=__shfl(w0,j), b1=__shfl(w1,j), b2=__shfl(w2,j), b3=__shfl(w3,j);
        float l = row[j];
        if (lane>j){ w0-=l*b0; w1-=l*b1; w2-=l*b2; w3-=l*b3; }
    }
    *(float4*)(W + (size_t)(h+lane)*4) = make_float4(w0,w1,w2,w3);
}

// ------------------------------------------------------------------
__global__ void k_build_A(const float* __restrict__ X, float* __restrict__ A){
    const int i  = blockIdx.y;
    const int j0 = (blockIdx.x*256 + threadIdx.x)*4;
    const float4 xi = *(const float4*)(X + (size_t)i*4);
    float out[4];
#pragma unroll
    for (int s=0;s<4;s++){
        const float4 xj = *(const float4*)(X + (size_t)(j0+s)*4);
        float d0=xi.x-xj.x, d1=xi.y-xj.y, d2=xi.z-xj.z, d3=xi.w-xj.w;
        float sq = d0*d0+d1*d1+d2*d2+d3*d3;
        float v  = __expf(-0.5f*sq);
        if (i == j0+s) v += 0.001f;
        out[s]=v;
    }
    *(float4*)(A + (size_t)i*LDA + j0) = make_float4(out[0],out[1],out[2],out[3]);
}

__global__ void k_init(const float* __restrict__ Z, float* __restrict__ W,
                       double* __restrict__ acc){
    const int i = blockIdx.x*256+threadIdx.x;
    ((float4*)W)[i] = ((const float4*)Z)[i];
    if (blockIdx.x==0 && threadIdx.x==0) acc[0]=0.0;
}

__global__ __launch_bounds__(256) void k_chol0(float* __restrict__ A, float* __restrict__ W){
    __shared__ float Dm[64*68];
    const int tid=threadIdx.x;
#pragma unroll
    for (int it=0; it<4; ++it){
        int idx=tid+it*256, r=idx>>4, q=idx&15;
        *(float4*)&Dm[r*68+q*4] = *(const float4*)(A + (size_t)r*LDA + q*4);
    }
    __syncthreads();
    if (tid<64){
        float4 w = *(const float4*)(W + (size_t)tid*4);
        wave_chol_solve(Dm, A, 0, w, W);
    }
}

// ------------------------------------------------------------------
// Fused per-step kernel. Roles by blockIdx: [0,nT) = T, [nT,nT+nP) = P, last = D.
__global__ __launch_bounds__(256) void k_F(float* __restrict__ A, float* __restrict__ W,
                                           float* __restrict__ Lp, int g){
    __shared__ float S_[13376];
    float* Ld   = S_;            // L(g,g) row-major [64][68]
    float* dinv = S_+4352;
    float* Wg   = S_+4416;       // W_g [64][4]
    float* LrT  = S_+4672;       // [t][r]
    float* LcT  = S_+9024;       // [t][r]  (also Dm for D)
    const int tid = threadIdx.x;
    const int g64 = g*64;
    const int pend = g|3;
    const bool hasD = (g&3)!=3;
    const int nT = (63-g+3)>>2;

    for (int it=0; it<4; ++it){
        int idx = tid + it*256, r = idx>>4, q = idx&15;
        *(float4*)&Ld[r*68+q*4] = *(const float4*)(A + (size_t)(g64+r)*LDA + g64 + q*4);
    }
    if (tid < 64) *(float4*)&Wg[tid*4] = *(const float4*)(W + (size_t)(g64+tid)*4);
    __syncthreads();
    if (tid < 64) dinv[tid] = 1.0f/Ld[tid*68+tid];
    __syncthreads();

    int bid = blockIdx.x;
    if (bid < nT){
        // ---------- T: substitution TRSM + W update ----------
        const int row = g64 + 64 + bid*256 + tid;
        const int rl  = row>4095 ? 4095 : row;
        float x[64];
        const float* src = A + (size_t)rl*LDA + g64;
#pragma unroll
        for (int q=0;q<16;q++){
            float4 v = *(const float4*)(src + q*4);
            x[q*4]=v.x; x[q*4+1]=v.y; x[q*4+2]=v.z; x[q*4+3]=v.w;
        }
#pragma unroll
        for (int c=0;c<64;c++){
            float xc = x[c]*dinv[c];
            x[c] = xc;
#pragma unroll
            for (int t=c+1;t<64;t++) x[t] -= xc*Ld[t*68 + c];
        }
        if (row < 4096){
            float* lp = Lp + (size_t)row*256 + (g&3)*64;
#pragma unroll
            for (int q=0;q<16;q++)
                *(float4*)(lp+q*4) = make_float4(x[q*4],x[q*4+1],x[q*4+2],x[q*4+3]);
            const bool skipW = hasD && ((row>>6) == g+1);
            if (!skipW){
                float4 wv = *(const float4*)(W + (size_t)row*4);
                float s0=0.f,s1=0.f,s2=0.f,s3=0.f;
#pragma unroll 16
                for (int t=0;t<64;t++){
                    float l = x[t];
                    float4 wg = *(const float4*)&Wg[t*4];
                    s0 += l*wg.x; s1 += l*wg.y; s2 += l*wg.z; s3 += l*wg.w;
                }
                wv.x-=s0; wv.y-=s1; wv.z-=s2; wv.w-=s3;
                *(float4*)(W + (size_t)row*4) = wv;
            }
        }
        return;
    }
    bid -= nT;

    // decode P tile
    int c_blk=-1, r_blk=-1;
    for (int c=g+1; c<=pend; ++c){
        int st = (c==g+1)? c+1 : c;
        int cnt = 64-st;
        if (c_blk<0){
            if (bid < cnt){ c_blk=c; r_blk=st+bid; }
            else bid -= cnt;
        }
    }
    const int tx = tid&15, ty = tid>>4;

    if (c_blk >= 0){
        // ---------- P: self-TRSM two tiles, rank-64 update ----------
        const bool dgp = (r_blk==c_blk);
        const int wv_ = tid>>6, lane = tid&63;
        if (wv_==0 || (wv_==1 && !dgp)){
            const int rb  = (wv_==0)? r_blk : c_blk;
            const int row = rb*64 + lane;
            float x[64];
            const float* src = A + (size_t)row*LDA + g64;
#pragma unroll
            for (int q=0;q<16;q++){
                float4 v = *(const float4*)(src + q*4);
                x[q*4]=v.x; x[q*4+1]=v.y; x[q*4+2]=v.z; x[q*4+3]=v.w;
            }
#pragma unroll
            for (int c=0;c<64;c++){
                float xc = x[c]*dinv[c];
                x[c] = xc;
#pragma unroll
                for (int t=c+1;t<64;t++) x[t] -= xc*Ld[t*68 + c];
            }
            float* dst = (wv_==0)? LrT : LcT;
#pragma unroll
            for (int t=0;t<64;t++) dst[t*68+lane] = x[t];
        }
        __syncthreads();
        const float* B = dgp ? LrT : LcT;
        float acc[4][4]={};
#pragma unroll 8
        for (int t=0;t<64;t++){
            float4 a = *(const float4*)&LrT[t*68 + ty*4];
            float4 b = *(const float4*)&B[t*68 + tx*4];
            acc[0][0]+=a.x*b.x; acc[0][1]+=a.x*b.y; acc[0][2]+=a.x*b.z; acc[0][3]+=a.x*b.w;
            acc[1][0]+=a.y*b.x; acc[1][1]+=a.y*b.y; acc[1][2]+=a.y*b.z; acc[1][3]+=a.y*b.w;
            acc[2][0]+=a.z*b.x; acc[2][1]+=a.z*b.y; acc[2][2]+=a.z*b.z; acc[2][3]+=a.z*b.w;
            acc[3][0]+=a.w*b.x; acc[3][1]+=a.w*b.y; acc[3][2]+=a.w*b.z; acc[3][3]+=a.w*b.w;
        }
        const int r0 = r_blk*64, c0 = c_blk*64;
#pragma unroll
        for (int ii=0;ii<4;ii++){
            float* p = A + (size_t)(r0+ty*4+ii)*LDA + c0 + tx*4;
            float4 cv = *(float4*)p;
            cv.x-=acc[ii][0]; cv.y-=acc[ii][1]; cv.z-=acc[ii][2]; cv.w-=acc[ii][3];
            *(float4*)p = cv;
        }
        return;
    }

    // ---------- D: next diag ----------
    {
        const int lane = tid&63;
        const int h = (g+1)*64;
        if (tid < 64){
            float x[64];
            const float* src = A + (size_t)(h+lane)*LDA + g64;
#pragma unroll
            for (int q=0;q<16;q++){
                float4 v = *(const float4*)(src + q*4);
                x[q*4]=v.x; x[q*4+1]=v.y; x[q*4+2]=v.z; x[q*4+3]=v.w;
            }
#pragma unroll
            for (int c=0;c<64;c++){
                float xc = x[c]*dinv[c];
                x[c] = xc;
#pragma unroll
                for (int t=c+1;t<64;t++) x[t] -= xc*Ld[t*68 + c];
            }
#pragma unroll
            for (int t=0;t<64;t++) LrT[t*68+lane] = x[t];
        }
        __syncthreads();
        float sacc[4][4]={};
#pragma unroll 8
        for (int t=0;t<64;t++){
            float4 a = *(const float4*)&LrT[t*68 + ty*4];
            float4 b = *(const float4*)&LrT[t*68 + tx*4];
            sacc[0][0]+=a.x*b.x; sacc[0][1]+=a.x*b.y; sacc[0][2]+=a.x*b.z; sacc[0][3]+=a.x*b.w;
            sacc[1][0]+=a.y*b.x; sacc[1][1]+=a.y*b.y; sacc[1][2]+=a.y*b.z; sacc[1][3]+=a.y*b.w;
            sacc[2][0]+=a.z*b.x; sacc[2][1]+=a.z*b.y; sacc[2][2]+=a.z*b.z; sacc[2][3]+=a.z*b.w;
            sacc[3][0]+=a.w*b.x; sacc[3][1]+=a.w*b.y; sacc[3][2]+=a.w*b.z; sacc[3][3]+=a.w*b.w;
        }
#pragma unroll
        for (int ii=0;ii<4;ii++){
            float4 c = *(const float4*)(A + (size_t)(h+ty*4+ii)*LDA + h + tx*4);
            c.x-=sacc[ii][0]; c.y-=sacc[ii][1]; c.z-=sacc[ii][2]; c.w-=sacc[ii][3];
            *(float4*)&LcT[(ty*4+ii)*68 + tx*4] = c;
        }
        __syncthreads();
        if (tid < 64){
            float4 w = *(const float4*)(W + (size_t)(h+lane)*4);
#pragma unroll 16
            for (int t=0;t<64;t++){
                float l = LrT[t*68+lane];
                float4 wg = *(const float4*)&Wg[t*4];
                w.x -= l*wg.x; w.y -= l*wg.y; w.z -= l*wg.z; w.w -= l*wg.w;
            }
            wave_chol_solve(LcT, A, h, w, W);
        }
    }
}

// ------------------------------------------------------------------
// Rank-256 trailing update from Lpanel (128x128 tiles) + fused next-head chol+W-solve.
__global__ __launch_bounds__(256) void k_upd256p(float* __restrict__ A, float* __restrict__ W,
                                                 const float* __restrict__ Lp, int S){
    __shared__ float S_[8704];
    const int tid = threadIdx.x;
    const int base = S*256 + 256;
    const int T2 = (4096-base)>>7;
    const int nT2 = T2*(T2+1)/2;
    const int tx = tid&15, ty = tid>>4;

    if ((int)blockIdx.x == nT2){
        // next head: rank-256 update + chol + W solve
        float* PT = S_;
        float* Dm = S_ + 4352;
        float acc[4][4]={};
        for (int kk=0; kk<4; ++kk){
            __syncthreads();
#pragma unroll
            for (int it=0; it<4; ++it){
                int ix = tid + it*256, r = ix>>4, q = ix&15;
                float4 v = *(const float4*)(Lp + (size_t)(base+r)*256 + kk*64 + q*4);
                PT[(q*4+0)*68+r]=v.x; PT[(q*4+1)*68+r]=v.y;
                PT[(q*4+2)*68+r]=v.z; PT[(q*4+3)*68+r]=v.w;
            }
            __syncthreads();
#pragma unroll 8
            for (int t=0;t<64;t++){
                float4 a = *(const float4*)&PT[t*68 + ty*4];
                float4 b = *(const float4*)&PT[t*68 + tx*4];
                acc[0][0]+=a.x*b.x; acc[0][1]+=a.x*b.y; acc[0][2]+=a.x*b.z; acc[0][3]+=a.x*b.w;
                acc[1][0]+=a.y*b.x; acc[1][1]+=a.y*b.y; acc[1][2]+=a.y*b.z; acc[1][3]+=a.y*b.w;
                acc[2][0]+=a.z*b.x; acc[2][1]+=a.z*b.y; acc[2][2]+=a.z*b.z; acc[2][3]+=a.z*b.w;
                acc[3][0]+=a.w*b.x; acc[3][1]+=a.w*b.y; acc[3][2]+=a.w*b.z; acc[3][3]+=a.w*b.w;
            }
        }
        __syncthreads();
#pragma unroll
        for (int ii=0;ii<4;ii++){
            float4 c = *(const float4*)(A + (size_t)(base+ty*4+ii)*LDA + base + tx*4);
            c.x-=acc[ii][0]; c.y-=acc[ii][1]; c.z-=acc[ii][2]; c.w-=acc[ii][3];
            *(float4*)&Dm[(ty*4+ii)*68 + tx*4] = c;
        }
        __syncthreads();
        if (tid < 64){
            float4 w = *(const float4*)(W + (size_t)(base+tid)*4);
            wave_chol_solve(Dm, A, base, w, W);
        }
        return;
    }

    float* Sa = S_;
    float* Sb = S_ + 4224;
    int t2 = blockIdx.x;
    int bi = (int)((sqrtf(8.f*(float)t2+1.f)-1.f)*0.5f);
    while ((bi+1)*(bi+2)/2 <= t2) ++bi;
    while (bi*(bi+1)/2 > t2) --bi;
    const int bj = t2 - bi*(bi+1)/2;
    const int r0 = base + bi*128, c0 = base + bj*128;
    const bool dg = (bi==bj);
    const float* Sbp = dg ? Sa : Sb;
    int row_[4], q_[4];
#pragma unroll
    for (int it=0;it<4;++it){ int ix=tid+it*256; row_[it]=ix>>3; q_[it]=ix&7; }
    float4 ra[4], rb[4];
#pragma unroll
    for (int it=0;it<4;++it){
        ra[it] = *(const float4*)(Lp + (size_t)(r0+row_[it])*256 + q_[it]*4);
        if (!dg) rb[it] = *(const float4*)(Lp + (size_t)(c0+row_[it])*256 + q_[it]*4);
    }
    float acc[8][8]={};
    for (int kk=0;kk<8;++kk){
        __syncthreads();
#pragma unroll
        for (int it=0;it<4;++it){
            Sa[(q_[it]*4+0)*132+row_[it]]=ra[it].x; Sa[(q_[it]*4+1)*132+row_[it]]=ra[it].y;
            Sa[(q_[it]*4+2)*132+row_[it]]=ra[it].z; Sa[(q_[it]*4+3)*132+row_[it]]=ra[it].w;
            if (!dg){
                Sb[(q_[it]*4+0)*132+row_[it]]=rb[it].x; Sb[(q_[it]*4+1)*132+row_[it]]=rb[it].y;
                Sb[(q_[it]*4+2)*132+row_[it]]=rb[it].z; Sb[(q_[it]*4+3)*132+row_[it]]=rb[it].w;
            }
        }
        __syncthreads();
        if (kk < 7){
            const int kb = (kk+1)*32;
#pragma unroll
            for (int it=0;it<4;++it){
                ra[it] = *(const float4*)(Lp + (size_t)(r0+row_[it])*256 + kb + q_[it]*4);
                if (!dg) rb[it] = *(const float4*)(Lp + (size_t)(c0+row_[it])*256 + kb + q_[it]*4);
            }
        }
#pragma unroll 4
        for (int t=0;t<32;++t){
            float4 a0 = *(const float4*)&Sa[t*132 + ty*8];
            float4 a1 = *(const float4*)&Sa[t*132 + ty*8 + 4];
            float4 b0 = *(const float4*)&Sbp[t*132 + tx*4];
            float4 b1 = *(const float4*)&Sbp[t*132 + 64 + tx*4];
            float av[8]={a0.x,a0.y,a0.z,a0.w,a1.x,a1.y,a1.z,a1.w};
            float bv[8]={b0.x,b0.y,b0.z,b0.w,b1.x,b1.y,b1.z,b1.w};
#pragma unroll
            for (int ii=0;ii<8;ii++)
#pragma unroll
                for (int jj=0;jj<8;jj++) acc[ii][jj] += av[ii]*bv[jj];
        }
    }
    // subtract-store; head 64x64 quadrant owned by the chol block
#pragma unroll
    for (int ii=0;ii<8;ii++){
        const int r = r0 + ty*8 + ii;
        const int c1 = c0 + tx*4;
        const int c2 = c0 + 64 + tx*4;
        if (!(r < base+64 && c1 < base+64)){
            float* p = A + (size_t)r*LDA + c1;
            float4 cv = *(float4*)p;
            cv.x-=acc[ii][0]; cv.y-=acc[ii][1]; cv.z-=acc[ii][2]; cv.w-=acc[ii][3];
            *(float4*)p = cv;
        }
        if (!(r < base+64 && c2 < base+64)){
            float* p = A + (size_t)r*LDA + c2;
            float4 cv = *(float4*)p;
            cv.x-=acc[ii][4]; cv.y-=acc[ii][5]; cv.z-=acc[ii][6]; cv.w-=acc[ii][7];
            *(float4*)p = cv;
        }
    }
}

// ------------------------------------------------------------------
__global__ void k_lossfit(const float* __restrict__ Z, const float* __restrict__ Y,
                          double* __restrict__ acc){
    const int tid=threadIdx.x;
    const int i0=blockIdx.x*8;
    double s=0.0;
    for (int ii=0;ii<8;ii++){
        const float4 zi = *(const float4*)(Z + (size_t)(i0+ii)*4);
        for (int j=tid;j<NN;j+=256){
            float4 zj = *(const float4*)(Z + (size_t)j*4);
            float4 yj = *(const float4*)(Y + (size_t)j*4);
            float d0=zi.x-zj.x, d1=zi.y-zj.y, d2=zi.z-zj.z, d3=zi.w-zj.w;
            float dzz = d0*d0+d1*d1+d2*d2+d3*d3;
            d0=zi.x-yj.x; d1=zi.y-yj.y; d2=zi.z-yj.z; d3=zi.w-yj.w;
            float dzy = d0*d0+d1*d1+d2*d2+d3*d3;
            s += (double)(__expf(-dzz) - 2.f*__expf(-dzy));
        }
    }
    for (int o=32;o;o>>=1) s += __shfl_down(s,o);
    __shared__ double ps[4];
    if ((tid&63)==0) ps[tid>>6]=s;
    __syncthreads();
    if (tid==0) atomicAdd(acc, ps[0]+ps[1]+ps[2]+ps[3]);
}

__global__ void k_finish(const float* __restrict__ W, const double* __restrict__ acc,
                         float* __restrict__ out){
    const int tid=threadIdx.x;
    double s=0.0;
    for (int r=tid;r<NN;r+=256){
        float4 v=*(const float4*)(W+(size_t)r*4);
        s += (double)v.x*v.x+(double)v.y*v.y+(double)v.z*v.z+(double)v.w*v.w;
    }
    for (int o=32;o;o>>=1) s += __shfl_down(s,o);
    __shared__ double ps[4];
    if ((tid&63)==0) ps[tid>>6]=s;
    __syncthreads();
    if (tid==0) out[0] = (float)(acc[0] + 0.01*(ps[0]+ps[1]+ps[2]+ps[3]));
}

// ------------------------------------------------------------------
extern "C" void kernel_launch(void* const* d_in, const int* in_sizes, int n_in,
                              void* d_out, int out_size, void* d_ws, size_t ws_size,
                              hipStream_t stream){
    const float* X=(const float*)d_in[0];
    const float* Y=(const float*)d_in[1];
    const float* Z=(const float*)d_in[2];
    float* ws   = (float*)d_ws;
    float* A    = ws;
    float* W    = ws + OFF_W;
    float* Lp   = ws + OFF_LP;
    double* acc = (double*)(ws + OFF_ACC);

    if (ws_size < (OFF_ACC+2)*sizeof(float) + 16) return;  // loud failure

    k_init   <<<16,256,0,stream>>>(Z, W, acc);
    k_build_A<<<dim3(NN/1024,NN),256,0,stream>>>(X, A);
    k_lossfit<<<512,256,0,stream>>>(Z, Y, acc);
    k_chol0  <<<1,256,0,stream>>>(A, W);

    for (int g=0; g<63; ++g){
        const int nT = (63-g+3)>>2;
        const int pend = g|3;
        int nP = 0;
        for (int c=g+1; c<=pend; ++c){
            int st = (c==g+1)? c+1 : c;
            nP += 64-st;
        }
        const int hasD = ((g&3)!=3) ? 1 : 0;
        k_F<<<nT+nP+hasD,256,0,stream>>>(A, W, Lp, g);
        if ((g&3)==3){
            const int S = g>>2;
            const int T2 = (4096-(S+1)*256)>>7;
            const int nT2 = T2*(T2+1)/2;
            k_upd256p<<<nT2+1,256,0,stream>>>(A, W, Lp, S);
        }
    }
    k_finish<<<1,256,0,stream>>>(W, acc, (float*)d_out);
}